// Round 6
// baseline (298.585 us; speedup 1.0000x reference)
//
#include <hip/hip_runtime.h>
#include <stdint.h>

using f32x16 = __attribute__((ext_vector_type(16))) float;
using short8 = __attribute__((ext_vector_type(8))) short;

#define DEVI static __device__ __forceinline__

// float -> bf16 round-to-nearest-even
DEVI unsigned short f2bf(float f) {
  unsigned u = __float_as_uint(f);
  u += 0x7FFFu + ((u >> 16) & 1u);
  return (unsigned short)(u >> 16);
}

// async global->LDS, 16B per lane. LDS dest is wave-uniform base; HW writes
// base + lane*16. Global src is per-lane.
DEVI void gld16(const void* g, void* l) {
  __builtin_amdgcn_global_load_lds(
      reinterpret_cast<const __attribute__((address_space(1))) unsigned int*>(
          reinterpret_cast<uintptr_t>(g)),
      reinterpret_cast<__attribute__((address_space(3))) unsigned int*>(
          reinterpret_cast<uintptr_t>(l)),
      16, 0, 0);
}

// ---------------- K0: zero bn stats + global zero page ----------------
__global__ void k_zero(float* __restrict__ bn, float* __restrict__ zp) {
  const int t = threadIdx.x;
  for (int i = t; i < 768; i += 256) bn[i] = 0.0f;
  for (int i = t; i < 1024; i += 256) zp[i] = 0.0f;
}

// ---------------- K1: per-(b,c) sum / sumsq of x ----------------
__global__ __launch_bounds__(256) void k_stats(const float* __restrict__ x,
                                               float* __restrict__ sums,
                                               float* __restrict__ sumsq) {
  const int bc = blockIdx.x;  // 0..12287
  const float4 v =
      reinterpret_cast<const float4*>(x + (size_t)bc * 1024)[threadIdx.x];
  float s = v.x + v.y + v.z + v.w;
  float q = v.x * v.x + v.y * v.y + v.z * v.z + v.w * v.w;
#pragma unroll
  for (int off = 1; off < 64; off <<= 1) {
    s += __shfl_xor(s, off, 64);
    q += __shfl_xor(q, off, 64);
  }
  __shared__ float ls[4], lq[4];
  const int wv = threadIdx.x >> 6;
  if ((threadIdx.x & 63) == 0) { ls[wv] = s; lq[wv] = q; }
  __syncthreads();
  if (threadIdx.x == 0) {
    sums[bc]  = ls[0] + ls[1] + ls[2] + ls[3];
    sumsq[bc] = lq[0] + lq[1] + lq[2] + lq[3];
  }
}

// ---------------- K2: fold both CSA blocks into fea2 = A*x + B ----------------
__global__ __launch_bounds__(384) void k_coef(
    const float* __restrict__ pmp, const float* __restrict__ psp,
    const float* __restrict__ pmn, const float* __restrict__ psn,
    const float* __restrict__ cw, const int* __restrict__ label,
    const float* __restrict__ sums, const float* __restrict__ sumsq,
    float* __restrict__ Ac, float* __restrict__ Bc) {
  const int b = blockIdx.x;    // 0..31
  const int c = threadIdx.x;   // 0..383
  __shared__ float w0[64], w1[64];
  if (threadIdx.x < 64) w0[threadIdx.x] = cw[b * 64 + threadIdx.x];
  else if (threadIdx.x < 128) w1[threadIdx.x - 64] = cw[2048 + b * 64 + (threadIdx.x - 64)];
  __syncthreads();
  const bool sel = (label[b] == 0);
  const float* m1t = (sel ? pmp : pmn);           // layer 0 tables [K=64][C=384]
  const float* s1t = (sel ? psp : psn);
  const float* m2t = m1t + 64 * 384;              // layer 1
  const float* s2t = s1t + 64 * 384;
  float m1 = 0.f, s1 = 0.f, m2 = 0.f, s2 = 0.f;
  for (int k = 0; k < 64; ++k) {
    const float a0 = w0[k], a1 = w1[k];
    m1 += a0 * m1t[k * 384 + c];
    s1 += a0 * s1t[k * 384 + c];
    m2 += a1 * m2t[k * 384 + c];
    s2 += a1 * s2t[k * 384 + c];
  }
  const int bc = b * 384 + c;
  const float sum = sums[bc], sq = sumsq[bc];
  const float mean = sum * (1.0f / 1024.0f);
  float var = (sq - sum * mean) * (1.0f / 1023.0f);  // ddof=1
  var = fmaxf(var, 0.0f);
  const float sd1 = sqrtf(var + 1e-5f);
  const float a1c = 1.0f + s1 / sd1;
  const float b1c = m1 - mean * (s1 / sd1);
  const float mean1 = a1c * mean + b1c;      // exact mean of affine fea1
  const float var1  = a1c * a1c * var;       // exact ddof=1 var of affine fea1
  const float sd2 = sqrtf(var1 + 1e-5f);
  const float t2 = 1.0f + s2 / sd2;
  Ac[bc] = a1c * t2;
  Bc[bc] = b1c * t2 + m2 - mean1 * (s2 / sd2);
}

// ---------------- K3: fea2 NHWC bf16 = A*x + B (LDS transpose for writes) ----
// grid (128,6): block = 256 pixels x 64 channels
__global__ __launch_bounds__(256) void k_fea(const float* __restrict__ x,
                                             const float* __restrict__ Ac,
                                             const float* __restrict__ Bc,
                                             unsigned short* __restrict__ fea) {
  __shared__ unsigned short tb[256][68];   // +4 pad: bank-conflict-free
  const int t = threadIdx.x;
  const int g0 = blockIdx.x << 8;          // pixel base
  const int b = g0 >> 10;                  // uniform per block
  const int c0 = blockIdx.y * 64;
  const float* xb = x + (((size_t)b * 384) << 10) + (g0 & 1023) + t;
  const float* Ab = Ac + b * 384 + c0;
  const float* Bb = Bc + b * 384 + c0;
#pragma unroll 1
  for (int u8 = 0; u8 < 64; u8 += 8) {
    union { unsigned short us[8]; uint4 v; } pk;
#pragma unroll
    for (int u = 0; u < 8; ++u) {
      const int c = u8 + u;
      pk.us[u] = f2bf(Ab[c] * xb[(size_t)(c0 + c) << 10] + Bb[c]);
    }
    *reinterpret_cast<uint4*>(&tb[t][u8]) = pk.v;
  }
  __syncthreads();
  const int j = t & 7;
#pragma unroll
  for (int rep = 0; rep < 8; ++rep) {
    const int p = rep * 32 + (t >> 3);
    const uint4 v = *reinterpret_cast<const uint4*>(&tb[p][j * 8]);
    *reinterpret_cast<uint4*>(fea + (size_t)(g0 + p) * 384 + c0 + j * 8) = v;
  }
}

// ---------------- K4: conv_w (OIHW f32) -> wb[tap][co][ci] bf16 ----------------
__global__ __launch_bounds__(256) void k_wcvt(const float* __restrict__ w,
                                              unsigned short* __restrict__ wb) {
  const int e = (blockIdx.x * 256 + threadIdx.x) * 4;  // 9*384*384 = 1327104 exact
  const int t = e / (384 * 384);
  const int rem = e - t * (384 * 384);
  const int co = rem / 384;
  const int ci = rem - co * 384;
  union { unsigned short us[4]; uint2 v; } pk;
#pragma unroll
  for (int u = 0; u < 4; ++u)
    pk.us[u] = f2bf(w[(size_t)(co * 384 + ci + u) * 9 + t]);
  *reinterpret_cast<uint2*>(wb + e) = pk.v;
}

// ---------------- K5: implicit-GEMM conv + BN partial stats ----------------
// 512 thr = 8 waves = 2 co-groups x 4 pixel-quarters (2 waves/SIMD).
// MFMA 32x32x16 bf16. Wave tile: 96co x 64pix = 3x2 frags (acc 96 VGPR).
// Block tile: 192co x 256pix (8 rows x 32 cols). ci-chunk = 16 -> 24 chunks.
// DOUBLE-BUFFERED LDS, buffer stride 69632 B (total 139264, 1 block/CU):
//   per buffer: [0,55296)      W: 9 taps x 192co rows of 32B (16ci), swizzled
//               [55296,65536)  IN: 10 hrows x 32 cols rows of 32B, swizzled
//               [65536,69632)  zero page
// Swizzle: 16B-half hh of row r stored at hh ^ (r&1) (both sides: source-
// permuted for gld16, XOR'd on ds_read) -> bank-balanced b128 reads.
// Pipeline: STAGE(next) issued BEFORE compute(cur); the compiler's vmcnt(0)
// drain at the trailing __syncthreads gives loads the whole compute to land.
__global__ __launch_bounds__(512, 2) void k_conv(
    const unsigned short* __restrict__ fea, const unsigned short* __restrict__ wb,
    const unsigned short* __restrict__ zpg, float* __restrict__ out,
    float* __restrict__ bn_sum, float* __restrict__ bn_sq) {
  __shared__ __align__(16) unsigned char lds[139264];
  const int tid = threadIdx.x;
  const int lane = tid & 63, wv = tid >> 6;      // wv 0..7
  const int wc = wv >> 2;                        // co group (0..1) -> 96 co
  const int wn = wv & 3;                         // pixel quarter -> 2 hrows
  const int pt = blockIdx.x;                     // 0..127
  const int ct = blockIdx.y;                     // 0..1
  const int b = pt >> 2, h0 = (pt & 3) * 8;
  const int co0 = ct * 192;
  const int BS = 69632;

  // zero both buffers' zero-pages
  for (int i = tid; i < 1024; i += 512) {
    reinterpret_cast<float*>(lds + 65536)[i] = 0.0f;
    reinterpret_cast<float*>(lds + BS + 65536)[i] = 0.0f;
  }

  // ---- hoisted LDS read addresses (buffer-relative) ----
  const int l31 = lane & 31, hb = lane >> 5;
  // A: row = wc*96 + m*32 + l31 (m via +1024 imm), 32B rows, swz key row&1
  const int arow = wc * 96 + l31;
  const int aoff = arow * 32 + ((hb ^ (arow & 1)) << 4);
  int baddr[2][3];
#pragma unroll
  for (int n = 0; n < 2; ++n) {
    const int r_out = wn * 2 + n;                // output hrow within strip
#pragma unroll
    for (int dx = 0; dx < 3; ++dx) {
      const int c = l31 + dx - 1;
      if ((unsigned)c < 32u) {
        const int pix = r_out * 32 + c;          // IN-tile row (dy via +1024)
        baddr[n][dx] = 55296 + pix * 32 + ((hb ^ (pix & 1)) << 4);
      } else {
        baddr[n][dx] = 65536 + lane * 16;        // zero page (+dy*1024 ok)
      }
    }
  }

  // ---- hoisted staging source pointers (advance +16 elems per chunk) ----
  // 64 slabs of 1024B: 0..53 = W, 54..63 = IN. Wave wv takes s = wv+8j.
  const unsigned short* gp[8];
  int gstep[8];
#pragma unroll
  for (int j = 0; j < 8; ++j) {
    const int s = wv + 8 * j;
    if (s < 54) {
      const int r = s * 32 + (lane >> 1);        // tap*192 + co, < 1728
      const int tap = ((r >> 6) * 11) >> 5;      // r/192 exact
      const int co = r - tap * 192;
      const int swzh = (lane & 1) ^ (r & 1);
      gp[j] = wb + (size_t)(tap * 384 + co0 + co) * 384 + swzh * 8;
      gstep[j] = 16;
    } else {
      const int s2 = s - 54;                     // IN hrow 0..9
      const int pcol = lane >> 1;
      const int h = h0 - 1 + s2;
      const int swzh = (lane & 1) ^ (pcol & 1);
      if (h >= 0 && h < 32) {
        gp[j] = fea + (size_t)((b * 32 + h) * 32 + pcol) * 384 + swzh * 8;
        gstep[j] = 16;
      } else {
        gp[j] = zpg + lane * 8;
        gstep[j] = 0;
      }
    }
  }

  f32x16 acc[3][2] = {};

#define STAGE(boff)                                    \
  do {                                                 \
    _Pragma("unroll")                                  \
    for (int j = 0; j < 8; ++j) {                      \
      gld16(gp[j], lds + (boff) + (wv + 8 * j) * 1024);\
      gp[j] += gstep[j];                               \
    }                                                  \
  } while (0)

  STAGE(0);
  __syncthreads();   // buf0 ready (compiler drains vmcnt+lgkm)

  for (int cc = 0; cc < 24; ++cc) {
    const int boff = (cc & 1) * BS;
    if (cc < 23) STAGE(((cc + 1) & 1) * BS);   // prefetch next chunk
    const unsigned char* base = lds + boff;
#pragma unroll
    for (int tap = 0; tap < 9; ++tap) {
      const int dy = tap / 3, dx = tap % 3;
      short8 af[3], bf[2];
#pragma unroll
      for (int m = 0; m < 3; ++m)
        af[m] = *reinterpret_cast<const short8*>(base + aoff + tap * 6144 + m * 1024);
#pragma unroll
      for (int n = 0; n < 2; ++n)
        bf[n] = *reinterpret_cast<const short8*>(base + baddr[n][dx] + dy * 1024);
#pragma unroll
      for (int m = 0; m < 3; ++m)
#pragma unroll
        for (int n = 0; n < 2; ++n)
          acc[m][n] = __builtin_amdgcn_mfma_f32_32x32x16_bf16(af[m], bf[n],
                                                              acc[m][n], 0, 0, 0);
    }
    __syncthreads();   // waits stage(cc+1) landed + reads of buf done
  }
#undef STAGE

  // ---- epilogue: store + BN partial stats ----
  // C/D map (32x32): col = lane&31, row = (reg&3) + 8*(reg>>2) + 4*(lane>>5)
  const size_t ob = ((size_t)(b * 384 + co0 + wc * 96) << 10) + h0 * 32;
#pragma unroll
  for (int m = 0; m < 3; ++m) {
#pragma unroll
    for (int r = 0; r < 16; ++r) {
      const int co = m * 32 + (r & 3) + 8 * (r >> 2) + 4 * hb;  // in wc group
      float s = 0.f, q = 0.f;
#pragma unroll
      for (int n = 0; n < 2; ++n) {
        const float v = acc[m][n][r];
        out[ob + ((size_t)co << 10) + (wn * 2 + n) * 32 + l31] = v;
        s += v; q += v * v;
      }
#pragma unroll
      for (int off = 1; off < 32; off <<= 1) {
        s += __shfl_xor(s, off, 64);
        q += __shfl_xor(q, off, 64);
      }
      if (l31 == 0) {
        atomicAdd(&bn_sum[co0 + wc * 96 + co], s);
        atomicAdd(&bn_sq[co0 + wc * 96 + co], q);
      }
    }
  }
}

// ---------------- K6: BN finalize in place ----------------
__global__ __launch_bounds__(256) void k_bnfin(float* __restrict__ y,
                                               const float* __restrict__ bn_sum,
                                               const float* __restrict__ bn_sq,
                                               const float* __restrict__ gamma,
                                               const float* __restrict__ beta) {
  const size_t N4 = (size_t)32 * 384 * 1024 / 4;
  const float inv = 1.0f / 32768.0f;
  for (size_t i = (size_t)blockIdx.x * 256 + threadIdx.x; i < N4;
       i += (size_t)gridDim.x * 256) {
    const size_t e = i * 4;
    const int c = (int)((e >> 10) % 384);
    const float mu = bn_sum[c] * inv;
    const float var = fmaxf(bn_sq[c] * inv - mu * mu, 0.0f);
    const float rs = rsqrtf(var + 1e-5f) * gamma[c];
    const float bt = beta[c];
    float4 v = *reinterpret_cast<float4*>(y + e);
    v.x = (v.x - mu) * rs + bt;
    v.y = (v.y - mu) * rs + bt;
    v.z = (v.z - mu) * rs + bt;
    v.w = (v.w - mu) * rs + bt;
    *reinterpret_cast<float4*>(y + e) = v;
  }
}

extern "C" void kernel_launch(void* const* d_in, const int* in_sizes, int n_in,
                              void* d_out, int out_size, void* d_ws, size_t ws_size,
                              hipStream_t stream) {
  const float* x     = (const float*)d_in[0];
  const float* pmp   = (const float*)d_in[1];
  const float* psp   = (const float*)d_in[2];
  const float* pmn   = (const float*)d_in[3];
  const float* psn   = (const float*)d_in[4];
  const float* cw    = (const float*)d_in[5];
  const float* convw = (const float*)d_in[6];
  const float* gamma = (const float*)d_in[7];
  const float* beta  = (const float*)d_in[8];
  const int*   label = (const int*)d_in[9];
  float* out = (float*)d_out;
  char* ws = (char*)d_ws;

  // ws layout (~28 MB total)
  unsigned short* fea = (unsigned short*)(ws);                 // 25165824 B
  unsigned short* wb  = (unsigned short*)(ws + 25165824);      //  2654208 B
  float* sums  = (float*)(ws + 27820032);                      //    49152 B
  float* sumsq = (float*)(ws + 27869184);                      //    49152 B
  float* Ac    = (float*)(ws + 27918336);                      //    49152 B
  float* Bc    = (float*)(ws + 27967488);                      //    49152 B
  float* bn    = (float*)(ws + 28016640);                      //     3072 B
  float* zp    = (float*)(ws + 28019712);                      //     4096 B

  k_zero<<<dim3(1), dim3(256), 0, stream>>>(bn, zp);
  k_stats<<<dim3(12288), dim3(256), 0, stream>>>(x, sums, sumsq);
  k_coef<<<dim3(32), dim3(384), 0, stream>>>(pmp, psp, pmn, psn, cw, label,
                                             sums, sumsq, Ac, Bc);
  k_fea<<<dim3(128, 6), dim3(256), 0, stream>>>(x, Ac, Bc, fea);
  k_wcvt<<<dim3(1296), dim3(256), 0, stream>>>(convw, wb);
  k_conv<<<dim3(128, 2), dim3(512), 0, stream>>>(fea, wb, (const unsigned short*)zp,
                                                 out, bn, bn + 384);
  k_bnfin<<<dim3(2048), dim3(256), 0, stream>>>(out, bn, bn + 384, gamma, beta);
}

// Round 7
// 235.293 us; speedup vs baseline: 1.2690x; 1.2690x over previous
//
#include <hip/hip_runtime.h>
#include <stdint.h>

using f32x4  = __attribute__((ext_vector_type(4))) float;
using short8 = __attribute__((ext_vector_type(8))) short;

#define DEVI static __device__ __forceinline__

// float -> bf16 round-to-nearest-even
DEVI unsigned short f2bf(float f) {
  unsigned u = __float_as_uint(f);
  u += 0x7FFFu + ((u >> 16) & 1u);
  return (unsigned short)(u >> 16);
}

// async global->LDS, 16B per lane. LDS dest is wave-uniform base; HW writes
// base + lane*16. Global src is per-lane.
DEVI void gld16(const void* g, void* l) {
  __builtin_amdgcn_global_load_lds(
      reinterpret_cast<const __attribute__((address_space(1))) unsigned int*>(
          reinterpret_cast<uintptr_t>(g)),
      reinterpret_cast<__attribute__((address_space(3))) unsigned int*>(
          reinterpret_cast<uintptr_t>(l)),
      16, 0, 0);
}

// ---------------- K0: zero bn stats + global zero page ----------------
__global__ void k_zero(float* __restrict__ bn, float* __restrict__ zp) {
  const int t = threadIdx.x;
  for (int i = t; i < 768; i += 256) bn[i] = 0.0f;
  for (int i = t; i < 1024; i += 256) zp[i] = 0.0f;
}

// ---------------- K1: per-(b,c) sum / sumsq of x ----------------
__global__ __launch_bounds__(256) void k_stats(const float* __restrict__ x,
                                               float* __restrict__ sums,
                                               float* __restrict__ sumsq) {
  const int bc = blockIdx.x;  // 0..12287
  const float4 v =
      reinterpret_cast<const float4*>(x + (size_t)bc * 1024)[threadIdx.x];
  float s = v.x + v.y + v.z + v.w;
  float q = v.x * v.x + v.y * v.y + v.z * v.z + v.w * v.w;
#pragma unroll
  for (int off = 1; off < 64; off <<= 1) {
    s += __shfl_xor(s, off, 64);
    q += __shfl_xor(q, off, 64);
  }
  __shared__ float ls[4], lq[4];
  const int wv = threadIdx.x >> 6;
  if ((threadIdx.x & 63) == 0) { ls[wv] = s; lq[wv] = q; }
  __syncthreads();
  if (threadIdx.x == 0) {
    sums[bc]  = ls[0] + ls[1] + ls[2] + ls[3];
    sumsq[bc] = lq[0] + lq[1] + lq[2] + lq[3];
  }
}

// ---------------- K2: fold both CSA blocks into fea2 = A*x + B ----------------
__global__ __launch_bounds__(384) void k_coef(
    const float* __restrict__ pmp, const float* __restrict__ psp,
    const float* __restrict__ pmn, const float* __restrict__ psn,
    const float* __restrict__ cw, const int* __restrict__ label,
    const float* __restrict__ sums, const float* __restrict__ sumsq,
    float* __restrict__ Ac, float* __restrict__ Bc) {
  const int b = blockIdx.x;    // 0..31
  const int c = threadIdx.x;   // 0..383
  __shared__ float w0[64], w1[64];
  if (threadIdx.x < 64) w0[threadIdx.x] = cw[b * 64 + threadIdx.x];
  else if (threadIdx.x < 128) w1[threadIdx.x - 64] = cw[2048 + b * 64 + (threadIdx.x - 64)];
  __syncthreads();
  const bool sel = (label[b] == 0);
  const float* m1t = (sel ? pmp : pmn);           // layer 0 tables [K=64][C=384]
  const float* s1t = (sel ? psp : psn);
  const float* m2t = m1t + 64 * 384;              // layer 1
  const float* s2t = s1t + 64 * 384;
  float m1 = 0.f, s1 = 0.f, m2 = 0.f, s2 = 0.f;
  for (int k = 0; k < 64; ++k) {
    const float a0 = w0[k], a1 = w1[k];
    m1 += a0 * m1t[k * 384 + c];
    s1 += a0 * s1t[k * 384 + c];
    m2 += a1 * m2t[k * 384 + c];
    s2 += a1 * s2t[k * 384 + c];
  }
  const int bc = b * 384 + c;
  const float sum = sums[bc], sq = sumsq[bc];
  const float mean = sum * (1.0f / 1024.0f);
  float var = (sq - sum * mean) * (1.0f / 1023.0f);  // ddof=1
  var = fmaxf(var, 0.0f);
  const float sd1 = sqrtf(var + 1e-5f);
  const float a1c = 1.0f + s1 / sd1;
  const float b1c = m1 - mean * (s1 / sd1);
  const float mean1 = a1c * mean + b1c;      // exact mean of affine fea1
  const float var1  = a1c * a1c * var;       // exact ddof=1 var of affine fea1
  const float sd2 = sqrtf(var1 + 1e-5f);
  const float t2 = 1.0f + s2 / sd2;
  Ac[bc] = a1c * t2;
  Bc[bc] = b1c * t2 + m2 - mean1 * (s2 / sd2);
}

// ---------------- K3: fea2 NHWC bf16 = A*x + B (LDS transpose for writes) ----
// grid (128,6): block = 256 pixels x 64 channels
__global__ __launch_bounds__(256) void k_fea(const float* __restrict__ x,
                                             const float* __restrict__ Ac,
                                             const float* __restrict__ Bc,
                                             unsigned short* __restrict__ fea) {
  __shared__ unsigned short tb[256][68];   // +4 pad: bank-conflict-free
  const int t = threadIdx.x;
  const int g0 = blockIdx.x << 8;          // pixel base
  const int b = g0 >> 10;                  // uniform per block
  const int c0 = blockIdx.y * 64;
  const float* xb = x + (((size_t)b * 384) << 10) + (g0 & 1023) + t;
  const float* Ab = Ac + b * 384 + c0;
  const float* Bb = Bc + b * 384 + c0;
#pragma unroll 1
  for (int u8 = 0; u8 < 64; u8 += 8) {
    union { unsigned short us[8]; uint4 v; } pk;
#pragma unroll
    for (int u = 0; u < 8; ++u) {
      const int c = u8 + u;
      pk.us[u] = f2bf(Ab[c] * xb[(size_t)(c0 + c) << 10] + Bb[c]);
    }
    *reinterpret_cast<uint4*>(&tb[t][u8]) = pk.v;
  }
  __syncthreads();
  const int j = t & 7;
#pragma unroll
  for (int rep = 0; rep < 8; ++rep) {
    const int p = rep * 32 + (t >> 3);
    const uint4 v = *reinterpret_cast<const uint4*>(&tb[p][j * 8]);
    *reinterpret_cast<uint4*>(fea + (size_t)(g0 + p) * 384 + c0 + j * 8) = v;
  }
}

// ---------------- K4: conv_w (OIHW f32) -> wb[tap][co][ci] bf16 ----------------
__global__ __launch_bounds__(256) void k_wcvt(const float* __restrict__ w,
                                              unsigned short* __restrict__ wb) {
  const int e = (blockIdx.x * 256 + threadIdx.x) * 4;  // 9*384*384 = 1327104 exact
  const int t = e / (384 * 384);
  const int rem = e - t * (384 * 384);
  const int co = rem / 384;
  const int ci = rem - co * 384;
  union { unsigned short us[4]; uint2 v; } pk;
#pragma unroll
  for (int u = 0; u < 4; ++u)
    pk.us[u] = f2bf(w[(size_t)(co * 384 + ci + u) * 9 + t]);
  *reinterpret_cast<uint2*>(wb + e) = pk.v;
}

// ---------------- K5: implicit-GEMM conv + BN partial stats ----------------
// 256 thr = 4 waves. Block tile: 96co x 256pix (8 rows x 32 cols).
// Wave tile: 96co x 64pix = 6x4 frags of 16x16x32 bf16 (acc 96 VGPR ->
// register headroom for compiler tap-level prefetch).
// DOUBLE-BUFFERED LDS (2 x 80896 = 161792 B, 1 block/CU):
//   per buffer: [0,55296)      W: 9 taps x 96co x 32ci (64B rows, grp swizzle)
//               [55296,75776)  IN: 10 hrows x 32 cols x 32ci (64B rows, swz)
//               [75776,80896)  zero page (covers +dy*2048 walk)
// Swizzle: grp d of row r stored at d ^ ((r>>1)&3); tap/m/dy-invariant.
// Pipeline (R6-validated order, R2-validated layout): STAGE(cc+1) issued
// BEFORE compute(cc); single trailing __syncthreads per chunk — the
// compiler's vmcnt(0) drain lands after compute, so staging flies under it.
__global__ __launch_bounds__(256, 1) void k_conv(
    const unsigned short* __restrict__ fea, const unsigned short* __restrict__ wb,
    const unsigned short* __restrict__ zpg, float* __restrict__ out,
    float* __restrict__ bn_sum, float* __restrict__ bn_sq) {
  __shared__ __align__(16) unsigned char lds[161792];
  const int tid = threadIdx.x;
  const int lane = tid & 63, wv = tid >> 6;
  const int pt = blockIdx.x;      // 0..127
  const int ct = blockIdx.y;      // 0..3
  const int b = pt >> 2, h0 = (pt & 3) * 8;
  const int co0 = ct * 96;
  const int wn = wv;              // pixel quarter
  const int BS = 80896;

  // zero BOTH buffers' zero-pages (drained by prologue __syncthreads)
  for (int i = tid; i < 1280; i += 256) {
    reinterpret_cast<float*>(lds + 75776)[i] = 0.0f;
    reinterpret_cast<float*>(lds + BS + 75776)[i] = 0.0f;
  }

  // ---- hoisted LDS read addresses (buffer-relative) ----
  const int l15 = lane & 15, d = lane >> 4;
  const int aoff = l15 * 64 + ((d ^ ((l15 >> 1) & 3)) << 4);
  int baddr[4][3];
#pragma unroll
  for (int n = 0; n < 4; ++n) {
    const int p_out = wn * 64 + n * 16 + l15;
    const int r_out = p_out >> 5, c_out = p_out & 31;
#pragma unroll
    for (int dx = 0; dx < 3; ++dx) {
      const int c = c_out + dx - 1;
      if ((unsigned)c < 32u) {
        const int pix = r_out * 32 + c;
        baddr[n][dx] = 55296 + pix * 64 + ((d ^ ((pix >> 1) & 3)) << 4);
      } else {
        baddr[n][dx] = 75776 + lane * 16;   // zero page (+dy*2048 stays zero)
      }
    }
  }

  // ---- hoisted staging source pointers (advance +64B per ci-chunk) ----
  const unsigned short* wp[14];
#pragma unroll
  for (int j = 0; j < 14; ++j) {
    const int s = wv + 4 * j;
    const int r = s * 16 + (lane >> 2);      // tap*96+co, < 864 when valid
    const int tap = (r * 683) >> 16;         // r/96 exact for r<864
    const int co = r - tap * 96;
    const int dd = (lane & 3) ^ ((co >> 1) & 3);
    wp[j] = wb + ((size_t)(tap * 384 + co0 + co) * 384 + dd * 8);
  }
  const unsigned short* ip[5];
  int istep[5];
#pragma unroll
  for (int j = 0; j < 5; ++j) {
    const int s = wv + 4 * j;
    const int pix = s * 16 + (lane >> 2);    // slab spans one prow
    const int prow = pix >> 5, pcol = pix & 31;
    const int h = h0 - 1 + prow;
    const int dd = (lane & 3) ^ ((pix >> 1) & 3);
    if (h >= 0 && h < 32) {
      ip[j] = fea + ((size_t)((b * 32 + h) * 32 + pcol) * 384 + dd * 8);
      istep[j] = 32;
    } else {
      ip[j] = zpg + lane * 8;
      istep[j] = 0;
    }
  }

  f32x4 acc[6][4] = {};

  // stage a chunk into buffer at byte offset boff, advance source pointers
#define STAGE(boff)                                              \
  do {                                                           \
    _Pragma("unroll")                                            \
    for (int j = 0; j < 14; ++j) {                               \
      if (j < 13 || wv < 2) {                                    \
        gld16(wp[j], lds + (boff) + (wv + 4 * j) * 1024);        \
        wp[j] += 32;                                             \
      }                                                          \
    }                                                            \
    _Pragma("unroll")                                            \
    for (int j = 0; j < 5; ++j) {                                \
      gld16(ip[j], lds + (boff) + 55296 + (wv + 4 * j) * 1024);  \
      ip[j] += istep[j];                                         \
    }                                                            \
  } while (0)

  STAGE(0);
  __syncthreads();                           // buf0 ready (compiler drains)

  for (int cc = 0; cc < 12; ++cc) {
    const int coff = (cc & 1) * BS;
    if (cc < 11) STAGE(((cc + 1) & 1) * BS); // prefetch next chunk first
    const unsigned char* base = lds + coff;
#pragma unroll
    for (int tap = 0; tap < 9; ++tap) {
      const int dy = tap / 3, dx = tap % 3;
      short8 af[6], bf[4];
#pragma unroll
      for (int m = 0; m < 6; ++m)
        af[m] = *reinterpret_cast<const short8*>(base + aoff + tap * 6144 + m * 1024);
#pragma unroll
      for (int n = 0; n < 4; ++n)
        bf[n] = *reinterpret_cast<const short8*>(base + baddr[n][dx] + dy * 2048);
#pragma unroll
      for (int m = 0; m < 6; ++m)
#pragma unroll
        for (int n = 0; n < 4; ++n)
          acc[m][n] = __builtin_amdgcn_mfma_f32_16x16x32_bf16(af[m], bf[n],
                                                              acc[m][n], 0, 0, 0);
    }
    __syncthreads();   // stage(cc+1) landed + all reads of buf[cc] done
  }
#undef STAGE

  // ---- epilogue: store + BN partial stats ----
  const size_t ob = (((size_t)b * 384 + co0) << 10) + h0 * 32;
#pragma unroll
  for (int m = 0; m < 6; ++m) {
#pragma unroll
    for (int r = 0; r < 4; ++r) {
      const int co = m * 16 + d * 4 + r;     // within co tile
      float s = 0.f, q = 0.f;
#pragma unroll
      for (int n = 0; n < 4; ++n) {
        const float v = acc[m][n][r];
        const int p = wn * 64 + n * 16 + l15;  // 0..255 within 8-row strip
        out[ob + ((size_t)co << 10) + p] = v;
        s += v; q += v * v;
      }
#pragma unroll
      for (int off = 1; off < 16; off <<= 1) {
        s += __shfl_xor(s, off, 64);
        q += __shfl_xor(q, off, 64);
      }
      if (l15 == 0) {
        atomicAdd(&bn_sum[co0 + co], s);
        atomicAdd(&bn_sq[co0 + co], q);
      }
    }
  }
}

// ---------------- K6: BN finalize in place ----------------
__global__ __launch_bounds__(256) void k_bnfin(float* __restrict__ y,
                                               const float* __restrict__ bn_sum,
                                               const float* __restrict__ bn_sq,
                                               const float* __restrict__ gamma,
                                               const float* __restrict__ beta) {
  const size_t N4 = (size_t)32 * 384 * 1024 / 4;
  const float inv = 1.0f / 32768.0f;
  for (size_t i = (size_t)blockIdx.x * 256 + threadIdx.x; i < N4;
       i += (size_t)gridDim.x * 256) {
    const size_t e = i * 4;
    const int c = (int)((e >> 10) % 384);
    const float mu = bn_sum[c] * inv;
    const float var = fmaxf(bn_sq[c] * inv - mu * mu, 0.0f);
    const float rs = rsqrtf(var + 1e-5f) * gamma[c];
    const float bt = beta[c];
    float4 v = *reinterpret_cast<float4*>(y + e);
    v.x = (v.x - mu) * rs + bt;
    v.y = (v.y - mu) * rs + bt;
    v.z = (v.z - mu) * rs + bt;
    v.w = (v.w - mu) * rs + bt;
    *reinterpret_cast<float4*>(y + e) = v;
  }
}

extern "C" void kernel_launch(void* const* d_in, const int* in_sizes, int n_in,
                              void* d_out, int out_size, void* d_ws, size_t ws_size,
                              hipStream_t stream) {
  const float* x     = (const float*)d_in[0];
  const float* pmp   = (const float*)d_in[1];
  const float* psp   = (const float*)d_in[2];
  const float* pmn   = (const float*)d_in[3];
  const float* psn   = (const float*)d_in[4];
  const float* cw    = (const float*)d_in[5];
  const float* convw = (const float*)d_in[6];
  const float* gamma = (const float*)d_in[7];
  const float* beta  = (const float*)d_in[8];
  const int*   label = (const int*)d_in[9];
  float* out = (float*)d_out;
  char* ws = (char*)d_ws;

  // ws layout (~28 MB total)
  unsigned short* fea = (unsigned short*)(ws);                 // 25165824 B
  unsigned short* wb  = (unsigned short*)(ws + 25165824);      //  2654208 B
  float* sums  = (float*)(ws + 27820032);                      //    49152 B
  float* sumsq = (float*)(ws + 27869184);                      //    49152 B
  float* Ac    = (float*)(ws + 27918336);                      //    49152 B
  float* Bc    = (float*)(ws + 27967488);                      //    49152 B
  float* bn    = (float*)(ws + 28016640);                      //     3072 B
  float* zp    = (float*)(ws + 28019712);                      //     4096 B

  k_zero<<<dim3(1), dim3(256), 0, stream>>>(bn, zp);
  k_stats<<<dim3(12288), dim3(256), 0, stream>>>(x, sums, sumsq);
  k_coef<<<dim3(32), dim3(384), 0, stream>>>(pmp, psp, pmn, psn, cw, label,
                                             sums, sumsq, Ac, Bc);
  k_fea<<<dim3(128, 6), dim3(256), 0, stream>>>(x, Ac, Bc, fea);
  k_wcvt<<<dim3(1296), dim3(256), 0, stream>>>(convw, wb);
  k_conv<<<dim3(128, 4), dim3(256), 0, stream>>>(fea, wb, (const unsigned short*)zp,
                                                 out, bn, bn + 384);
  k_bnfin<<<dim3(2048), dim3(256), 0, stream>>>(out, bn, bn + 384, gamma, beta);
}

// Round 8
// 214.076 us; speedup vs baseline: 1.3948x; 1.0991x over previous
//
#include <hip/hip_runtime.h>
#include <stdint.h>

using f32x4  = __attribute__((ext_vector_type(4))) float;
using short8 = __attribute__((ext_vector_type(8))) short;

#define DEVI static __device__ __forceinline__

// float -> bf16 round-to-nearest-even
DEVI unsigned short f2bf(float f) {
  unsigned u = __float_as_uint(f);
  u += 0x7FFFu + ((u >> 16) & 1u);
  return (unsigned short)(u >> 16);
}

// async global->LDS, 16B per lane. LDS dest is wave-uniform base; HW writes
// base + lane*16. Global src is per-lane.
DEVI void gld16(const void* g, void* l) {
  __builtin_amdgcn_global_load_lds(
      reinterpret_cast<const __attribute__((address_space(1))) unsigned int*>(
          reinterpret_cast<uintptr_t>(g)),
      reinterpret_cast<__attribute__((address_space(3))) unsigned int*>(
          reinterpret_cast<uintptr_t>(l)),
      16, 0, 0);
}

// ---------------- K0: zero bn stats + global zero page ----------------
__global__ void k_zero(float* __restrict__ bn, float* __restrict__ zp) {
  const int t = threadIdx.x;
  for (int i = t; i < 768; i += 256) bn[i] = 0.0f;
  for (int i = t; i < 1024; i += 256) zp[i] = 0.0f;
}

// ---------------- K1: per-(b,c) sum / sumsq of x ----------------
__global__ __launch_bounds__(256) void k_stats(const float* __restrict__ x,
                                               float* __restrict__ sums,
                                               float* __restrict__ sumsq) {
  const int bc = blockIdx.x;  // 0..12287
  const float4 v =
      reinterpret_cast<const float4*>(x + (size_t)bc * 1024)[threadIdx.x];
  float s = v.x + v.y + v.z + v.w;
  float q = v.x * v.x + v.y * v.y + v.z * v.z + v.w * v.w;
#pragma unroll
  for (int off = 1; off < 64; off <<= 1) {
    s += __shfl_xor(s, off, 64);
    q += __shfl_xor(q, off, 64);
  }
  __shared__ float ls[4], lq[4];
  const int wv = threadIdx.x >> 6;
  if ((threadIdx.x & 63) == 0) { ls[wv] = s; lq[wv] = q; }
  __syncthreads();
  if (threadIdx.x == 0) {
    sums[bc]  = ls[0] + ls[1] + ls[2] + ls[3];
    sumsq[bc] = lq[0] + lq[1] + lq[2] + lq[3];
  }
}

// ---------------- K2: fold both CSA blocks into fea2 = A*x + B ----------------
__global__ __launch_bounds__(384) void k_coef(
    const float* __restrict__ pmp, const float* __restrict__ psp,
    const float* __restrict__ pmn, const float* __restrict__ psn,
    const float* __restrict__ cw, const int* __restrict__ label,
    const float* __restrict__ sums, const float* __restrict__ sumsq,
    float* __restrict__ Ac, float* __restrict__ Bc) {
  const int b = blockIdx.x;    // 0..31
  const int c = threadIdx.x;   // 0..383
  __shared__ float w0[64], w1[64];
  if (threadIdx.x < 64) w0[threadIdx.x] = cw[b * 64 + threadIdx.x];
  else if (threadIdx.x < 128) w1[threadIdx.x - 64] = cw[2048 + b * 64 + (threadIdx.x - 64)];
  __syncthreads();
  const bool sel = (label[b] == 0);
  const float* m1t = (sel ? pmp : pmn);           // layer 0 tables [K=64][C=384]
  const float* s1t = (sel ? psp : psn);
  const float* m2t = m1t + 64 * 384;              // layer 1
  const float* s2t = s1t + 64 * 384;
  float m1 = 0.f, s1 = 0.f, m2 = 0.f, s2 = 0.f;
  for (int k = 0; k < 64; ++k) {
    const float a0 = w0[k], a1 = w1[k];
    m1 += a0 * m1t[k * 384 + c];
    s1 += a0 * s1t[k * 384 + c];
    m2 += a1 * m2t[k * 384 + c];
    s2 += a1 * s2t[k * 384 + c];
  }
  const int bc = b * 384 + c;
  const float sum = sums[bc], sq = sumsq[bc];
  const float mean = sum * (1.0f / 1024.0f);
  float var = (sq - sum * mean) * (1.0f / 1023.0f);  // ddof=1
  var = fmaxf(var, 0.0f);
  const float sd1 = sqrtf(var + 1e-5f);
  const float a1c = 1.0f + s1 / sd1;
  const float b1c = m1 - mean * (s1 / sd1);
  const float mean1 = a1c * mean + b1c;      // exact mean of affine fea1
  const float var1  = a1c * a1c * var;       // exact ddof=1 var of affine fea1
  const float sd2 = sqrtf(var1 + 1e-5f);
  const float t2 = 1.0f + s2 / sd2;
  Ac[bc] = a1c * t2;
  Bc[bc] = b1c * t2 + m2 - mean1 * (s2 / sd2);
}

// ---------------- K3: fea2 NHWC bf16 = A*x + B (LDS transpose for writes) ----
// grid (128,6): block = 256 pixels x 64 channels
__global__ __launch_bounds__(256) void k_fea(const float* __restrict__ x,
                                             const float* __restrict__ Ac,
                                             const float* __restrict__ Bc,
                                             unsigned short* __restrict__ fea) {
  __shared__ unsigned short tb[256][68];   // +4 pad: bank-conflict-free
  const int t = threadIdx.x;
  const int g0 = blockIdx.x << 8;          // pixel base
  const int b = g0 >> 10;                  // uniform per block
  const int c0 = blockIdx.y * 64;
  const float* xb = x + (((size_t)b * 384) << 10) + (g0 & 1023) + t;
  const float* Ab = Ac + b * 384 + c0;
  const float* Bb = Bc + b * 384 + c0;
#pragma unroll 1
  for (int u8 = 0; u8 < 64; u8 += 8) {
    union { unsigned short us[8]; uint4 v; } pk;
#pragma unroll
    for (int u = 0; u < 8; ++u) {
      const int c = u8 + u;
      pk.us[u] = f2bf(Ab[c] * xb[(size_t)(c0 + c) << 10] + Bb[c]);
    }
    *reinterpret_cast<uint4*>(&tb[t][u8]) = pk.v;
  }
  __syncthreads();
  const int j = t & 7;
#pragma unroll
  for (int rep = 0; rep < 8; ++rep) {
    const int p = rep * 32 + (t >> 3);
    const uint4 v = *reinterpret_cast<const uint4*>(&tb[p][j * 8]);
    *reinterpret_cast<uint4*>(fea + (size_t)(g0 + p) * 384 + c0 + j * 8) = v;
  }
}

// ---------------- K4: conv_w (OIHW f32) -> wb[tap][co][ci] bf16 ----------------
__global__ __launch_bounds__(256) void k_wcvt(const float* __restrict__ w,
                                              unsigned short* __restrict__ wb) {
  const int e = (blockIdx.x * 256 + threadIdx.x) * 4;  // 9*384*384 = 1327104 exact
  const int t = e / (384 * 384);
  const int rem = e - t * (384 * 384);
  const int co = rem / 384;
  const int ci = rem - co * 384;
  union { unsigned short us[4]; uint2 v; } pk;
#pragma unroll
  for (int u = 0; u < 4; ++u)
    pk.us[u] = f2bf(w[(size_t)(co * 384 + ci + u) * 9 + t]);
  *reinterpret_cast<uint2*>(wb + e) = pk.v;
}

// ---------------- K5: implicit-GEMM conv + BN partial stats ----------------
// 256 thr = 4 waves. Block tile: 96co x 256pix (8 rows x 32 cols).
// Wave tile: 96co x 64pix = 6x4 frags of 16x16x32 bf16 (acc 96 VGPR).
// K-steps at (ci-chunk, tap) granularity: 12 chunks x 9 taps = 108 steps.
// LDS 63488 B -> TWO blocks/CU (2 waves/SIMD) WITH full double-buffering:
//   [0,6144)        W buf 0: one tap-slice, 96co x 32ci (64B rows, swizzled)
//   [6144,12288)    W buf 1
//   [12288,37888)   IN buf 0: 10 hrows x 32 cols x 32ci (20480) + zp (5120)
//   [37888,63488)   IN buf 1 + zp
// Swizzle (R2-verified): grp d of row r stored at d ^ ((r>>1)&3).
// Pipeline: per step stage W(next tap) early; IN slabs spread 1/wave every
// other step; one __syncthreads per step. Block B computes through block A's
// vmcnt drains (2 blocks/CU TLP is the verified win condition).
__global__ __launch_bounds__(256, 2) void k_conv(
    const unsigned short* __restrict__ fea, const unsigned short* __restrict__ wb,
    const unsigned short* __restrict__ zpg, float* __restrict__ out,
    float* __restrict__ bn_sum, float* __restrict__ bn_sq) {
  __shared__ __align__(16) unsigned char lds[63488];
  const int tid = threadIdx.x;
  const int lane = tid & 63, wv = tid >> 6;
  const int pt = blockIdx.x;      // 0..127
  const int ct = blockIdx.y;      // 0..3
  const int b = pt >> 2, h0 = (pt & 3) * 8;
  const int co0 = ct * 96;
  const int wn = wv;              // pixel quarter
  const long long TS = 147456;    // tap stride in wb (elems)

  // zero both IN buffers' zero-pages
  for (int i = tid; i < 1280; i += 256) {
    reinterpret_cast<float*>(lds + 32768)[i] = 0.0f;
    reinterpret_cast<float*>(lds + 58368)[i] = 0.0f;
  }

  // ---- hoisted LDS read addresses ----
  const int l15 = lane & 15, d = lane >> 4;
  const int aoff = l15 * 64 + ((d ^ ((l15 >> 1) & 3)) << 4);   // within W buf
  int baddr[4][3];                                             // within IN buf
#pragma unroll
  for (int n = 0; n < 4; ++n) {
    const int p_out = wn * 64 + n * 16 + l15;
    const int r_out = p_out >> 5, c_out = p_out & 31;
#pragma unroll
    for (int dx = 0; dx < 3; ++dx) {
      const int c = c_out + dx - 1;
      if ((unsigned)c < 32u) {
        const int pix = r_out * 32 + c;
        baddr[n][dx] = pix * 64 + ((d ^ ((pix >> 1) & 3)) << 4);
      } else {
        baddr[n][dx] = 20480 + lane * 16;   // zp (+dy*2048 stays inside)
      }
    }
  }

  // ---- W staging pointers: wave wv owns slab wv (and 4+wv if wv<2) ----
  const int wr_a = wv * 16 + (lane >> 2);
  const int wr_b = (4 + wv) * 16 + (lane >> 2);
  const int wdd = (lane & 3) ^ ((lane >> 3) & 3);
  const unsigned short* wpa = wb + (size_t)(co0 + wr_a) * 384 + wdd * 8;
  const unsigned short* wpb = wb + (size_t)(co0 + wr_b) * 384 + wdd * 8;

  // ---- IN staging pointers (slab wv+4j), advance +32 per chunk ----
  const unsigned short* ip[5];
  int istep[5];
#pragma unroll
  for (int j = 0; j < 5; ++j) {
    const int s = wv + 4 * j;
    const int pix = s * 16 + (lane >> 2);
    const int prow = pix >> 5, pcol = pix & 31;
    const int h = h0 - 1 + prow;
    const int dd = (lane & 3) ^ ((pix >> 1) & 3);
    if (h >= 0 && h < 32) {
      ip[j] = fea + ((size_t)((b * 32 + h) * 32 + pcol) * 384 + dd * 8);
      istep[j] = 32;
    } else {
      ip[j] = zpg + lane * 8;
      istep[j] = 0;
    }
  }

  f32x4 acc[6][4] = {};

  // ---- prologue: stage W(0,0) -> wbuf0, IN(0) -> ibuf0 ----
  gld16(wpa, lds + wv * 1024);
  wpa += TS;
  if (wv < 2) { gld16(wpb, lds + (4 + wv) * 1024); }
  wpb += TS;
#pragma unroll
  for (int j = 0; j < 5; ++j) {
    gld16(ip[j], lds + 12288 + (wv + 4 * j) * 1024);
    ip[j] += istep[j];
  }
  __syncthreads();

  for (int cc = 0; cc < 12; cc += 2) {
#pragma unroll
    for (int t = 0; t < 18; ++t) {
      // --- stage W(kk+1) into wbuf[(t+1)&1] ---
      if (!(cc == 10 && t == 17)) {
        const int wsel = (t + 1) & 1;
        gld16(wpa, lds + wsel * 6144 + wv * 1024);
        if (wv < 2) gld16(wpb, lds + wsel * 6144 + (4 + wv) * 1024);
        const long long adv = (((t + 1) % 9) == 8) ? (32 - 8 * TS) : TS;
        wpa += adv; wpb += adv;
      }
      // --- stage IN slabs, spread: t=0,2,4,6,8 -> chunk cc+1 (ibuf1) ---
      if (t < 10 && (t & 1) == 0) {
        const int j = t >> 1;
        gld16(ip[j], lds + 37888 + (wv + 4 * j) * 1024);
        ip[j] += istep[j];
      }
      // --- t=9,11,13,15,17 -> chunk cc+2 (ibuf0), last pair guarded ---
      if (t >= 9 && ((t - 9) & 1) == 0) {
        if (cc < 10) {
          const int j = (t - 9) >> 1;
          gld16(ip[j], lds + 12288 + (wv + 4 * j) * 1024);
          ip[j] += istep[j];
        }
      }
      // --- compute one tap ---
      const int tap = t % 9, dy = tap / 3, dx = tap % 3;
      const unsigned char* wbase = lds + (t & 1) * 6144;
      const unsigned char* ibase = lds + 12288 + (t < 9 ? 0 : 25600);
      short8 af[6], bf[4];
#pragma unroll
      for (int m = 0; m < 6; ++m)
        af[m] = *reinterpret_cast<const short8*>(wbase + aoff + m * 1024);
#pragma unroll
      for (int n = 0; n < 4; ++n)
        bf[n] = *reinterpret_cast<const short8*>(ibase + baddr[n][dx] + dy * 2048);
#pragma unroll
      for (int m = 0; m < 6; ++m)
#pragma unroll
        for (int n = 0; n < 4; ++n)
          acc[m][n] = __builtin_amdgcn_mfma_f32_16x16x32_bf16(af[m], bf[n],
                                                              acc[m][n], 0, 0, 0);
      __syncthreads();
    }
  }

  // ---- epilogue: store + BN partial stats ----
  const size_t ob = (((size_t)b * 384 + co0) << 10) + h0 * 32;
#pragma unroll
  for (int m = 0; m < 6; ++m) {
#pragma unroll
    for (int r = 0; r < 4; ++r) {
      const int co = m * 16 + d * 4 + r;     // within co tile
      float s = 0.f, q = 0.f;
#pragma unroll
      for (int n = 0; n < 4; ++n) {
        const float v = acc[m][n][r];
        const int p = wn * 64 + n * 16 + l15;  // 0..255 within 8-row strip
        out[ob + ((size_t)co << 10) + p] = v;
        s += v; q += v * v;
      }
#pragma unroll
      for (int off = 1; off < 16; off <<= 1) {
        s += __shfl_xor(s, off, 64);
        q += __shfl_xor(q, off, 64);
      }
      if (l15 == 0) {
        atomicAdd(&bn_sum[co0 + co], s);
        atomicAdd(&bn_sq[co0 + co], q);
      }
    }
  }
}

// ---------------- K6: BN finalize in place ----------------
__global__ __launch_bounds__(256) void k_bnfin(float* __restrict__ y,
                                               const float* __restrict__ bn_sum,
                                               const float* __restrict__ bn_sq,
                                               const float* __restrict__ gamma,
                                               const float* __restrict__ beta) {
  const size_t N4 = (size_t)32 * 384 * 1024 / 4;
  const float inv = 1.0f / 32768.0f;
  for (size_t i = (size_t)blockIdx.x * 256 + threadIdx.x; i < N4;
       i += (size_t)gridDim.x * 256) {
    const size_t e = i * 4;
    const int c = (int)((e >> 10) % 384);
    const float mu = bn_sum[c] * inv;
    const float var = fmaxf(bn_sq[c] * inv - mu * mu, 0.0f);
    const float rs = rsqrtf(var + 1e-5f) * gamma[c];
    const float bt = beta[c];
    float4 v = *reinterpret_cast<float4*>(y + e);
    v.x = (v.x - mu) * rs + bt;
    v.y = (v.y - mu) * rs + bt;
    v.z = (v.z - mu) * rs + bt;
    v.w = (v.w - mu) * rs + bt;
    *reinterpret_cast<float4*>(y + e) = v;
  }
}

extern "C" void kernel_launch(void* const* d_in, const int* in_sizes, int n_in,
                              void* d_out, int out_size, void* d_ws, size_t ws_size,
                              hipStream_t stream) {
  const float* x     = (const float*)d_in[0];
  const float* pmp   = (const float*)d_in[1];
  const float* psp   = (const float*)d_in[2];
  const float* pmn   = (const float*)d_in[3];
  const float* psn   = (const float*)d_in[4];
  const float* cw    = (const float*)d_in[5];
  const float* convw = (const float*)d_in[6];
  const float* gamma = (const float*)d_in[7];
  const float* beta  = (const float*)d_in[8];
  const int*   label = (const int*)d_in[9];
  float* out = (float*)d_out;
  char* ws = (char*)d_ws;

  // ws layout (~28 MB total)
  unsigned short* fea = (unsigned short*)(ws);                 // 25165824 B
  unsigned short* wb  = (unsigned short*)(ws + 25165824);      //  2654208 B
  float* sums  = (float*)(ws + 27820032);                      //    49152 B
  float* sumsq = (float*)(ws + 27869184);                      //    49152 B
  float* Ac    = (float*)(ws + 27918336);                      //    49152 B
  float* Bc    = (float*)(ws + 27967488);                      //    49152 B
  float* bn    = (float*)(ws + 28016640);                      //     3072 B
  float* zp    = (float*)(ws + 28019712);                      //     4096 B

  k_zero<<<dim3(1), dim3(256), 0, stream>>>(bn, zp);
  k_stats<<<dim3(12288), dim3(256), 0, stream>>>(x, sums, sumsq);
  k_coef<<<dim3(32), dim3(384), 0, stream>>>(pmp, psp, pmn, psn, cw, label,
                                             sums, sumsq, Ac, Bc);
  k_fea<<<dim3(128, 6), dim3(256), 0, stream>>>(x, Ac, Bc, fea);
  k_wcvt<<<dim3(1296), dim3(256), 0, stream>>>(convw, wb);
  k_conv<<<dim3(128, 4), dim3(256), 0, stream>>>(fea, wb, (const unsigned short*)zp,
                                                 out, bn, bn + 384);
  k_bnfin<<<dim3(2048), dim3(256), 0, stream>>>(out, bn, bn + 384, gamma, beta);
}

// Round 9
// 203.530 us; speedup vs baseline: 1.4670x; 1.0518x over previous
//
#include <hip/hip_runtime.h>
#include <stdint.h>

using f32x4  = __attribute__((ext_vector_type(4))) float;
using short8 = __attribute__((ext_vector_type(8))) short;

#define DEVI static __device__ __forceinline__

// float -> bf16 round-to-nearest-even
DEVI unsigned short f2bf(float f) {
  unsigned u = __float_as_uint(f);
  u += 0x7FFFu + ((u >> 16) & 1u);
  return (unsigned short)(u >> 16);
}

// async global->LDS, 16B per lane. LDS dest is wave-uniform base; HW writes
// base + lane*16. Global src is per-lane.
DEVI void gld16(const void* g, void* l) {
  __builtin_amdgcn_global_load_lds(
      reinterpret_cast<const __attribute__((address_space(1))) unsigned int*>(
          reinterpret_cast<uintptr_t>(g)),
      reinterpret_cast<__attribute__((address_space(3))) unsigned int*>(
          reinterpret_cast<uintptr_t>(l)),
      16, 0, 0);
}

// ---------------- K0: zero bn stats + global zero page ----------------
__global__ void k_zero(float* __restrict__ bn, float* __restrict__ zp) {
  const int t = threadIdx.x;
  for (int i = t; i < 768; i += 256) bn[i] = 0.0f;
  for (int i = t; i < 1024; i += 256) zp[i] = 0.0f;
}

// ---------------- K1: per-(b,c) sum / sumsq of x ----------------
__global__ __launch_bounds__(256) void k_stats(const float* __restrict__ x,
                                               float* __restrict__ sums,
                                               float* __restrict__ sumsq) {
  const int bc = blockIdx.x;  // 0..12287
  const float4 v =
      reinterpret_cast<const float4*>(x + (size_t)bc * 1024)[threadIdx.x];
  float s = v.x + v.y + v.z + v.w;
  float q = v.x * v.x + v.y * v.y + v.z * v.z + v.w * v.w;
#pragma unroll
  for (int off = 1; off < 64; off <<= 1) {
    s += __shfl_xor(s, off, 64);
    q += __shfl_xor(q, off, 64);
  }
  __shared__ float ls[4], lq[4];
  const int wv = threadIdx.x >> 6;
  if ((threadIdx.x & 63) == 0) { ls[wv] = s; lq[wv] = q; }
  __syncthreads();
  if (threadIdx.x == 0) {
    sums[bc]  = ls[0] + ls[1] + ls[2] + ls[3];
    sumsq[bc] = lq[0] + lq[1] + lq[2] + lq[3];
  }
}

// ---------------- K2: fold both CSA blocks into fea2 = A*x + B ----------------
__global__ __launch_bounds__(384) void k_coef(
    const float* __restrict__ pmp, const float* __restrict__ psp,
    const float* __restrict__ pmn, const float* __restrict__ psn,
    const float* __restrict__ cw, const int* __restrict__ label,
    const float* __restrict__ sums, const float* __restrict__ sumsq,
    float* __restrict__ Ac, float* __restrict__ Bc) {
  const int b = blockIdx.x;    // 0..31
  const int c = threadIdx.x;   // 0..383
  __shared__ float w0[64], w1[64];
  if (threadIdx.x < 64) w0[threadIdx.x] = cw[b * 64 + threadIdx.x];
  else if (threadIdx.x < 128) w1[threadIdx.x - 64] = cw[2048 + b * 64 + (threadIdx.x - 64)];
  __syncthreads();
  const bool sel = (label[b] == 0);
  const float* m1t = (sel ? pmp : pmn);           // layer 0 tables [K=64][C=384]
  const float* s1t = (sel ? psp : psn);
  const float* m2t = m1t + 64 * 384;              // layer 1
  const float* s2t = s1t + 64 * 384;
  float m1 = 0.f, s1 = 0.f, m2 = 0.f, s2 = 0.f;
  for (int k = 0; k < 64; ++k) {
    const float a0 = w0[k], a1 = w1[k];
    m1 += a0 * m1t[k * 384 + c];
    s1 += a0 * s1t[k * 384 + c];
    m2 += a1 * m2t[k * 384 + c];
    s2 += a1 * s2t[k * 384 + c];
  }
  const int bc = b * 384 + c;
  const float sum = sums[bc], sq = sumsq[bc];
  const float mean = sum * (1.0f / 1024.0f);
  float var = (sq - sum * mean) * (1.0f / 1023.0f);  // ddof=1
  var = fmaxf(var, 0.0f);
  const float sd1 = sqrtf(var + 1e-5f);
  const float a1c = 1.0f + s1 / sd1;
  const float b1c = m1 - mean * (s1 / sd1);
  const float mean1 = a1c * mean + b1c;      // exact mean of affine fea1
  const float var1  = a1c * a1c * var;       // exact ddof=1 var of affine fea1
  const float sd2 = sqrtf(var1 + 1e-5f);
  const float t2 = 1.0f + s2 / sd2;
  Ac[bc] = a1c * t2;
  Bc[bc] = b1c * t2 + m2 - mean1 * (s2 / sd2);
}

// ---------------- K3: fea2 NHWC bf16 = A*x + B (LDS transpose for writes) ----
// grid (128,6): block = 256 pixels x 64 channels
__global__ __launch_bounds__(256) void k_fea(const float* __restrict__ x,
                                             const float* __restrict__ Ac,
                                             const float* __restrict__ Bc,
                                             unsigned short* __restrict__ fea) {
  __shared__ unsigned short tb[256][68];   // +4 pad: bank-conflict-free
  const int t = threadIdx.x;
  const int g0 = blockIdx.x << 8;          // pixel base
  const int b = g0 >> 10;                  // uniform per block
  const int c0 = blockIdx.y * 64;
  const float* xb = x + (((size_t)b * 384) << 10) + (g0 & 1023) + t;
  const float* Ab = Ac + b * 384 + c0;
  const float* Bb = Bc + b * 384 + c0;
#pragma unroll 1
  for (int u8 = 0; u8 < 64; u8 += 8) {
    union { unsigned short us[8]; uint4 v; } pk;
#pragma unroll
    for (int u = 0; u < 8; ++u) {
      const int c = u8 + u;
      pk.us[u] = f2bf(Ab[c] * xb[(size_t)(c0 + c) << 10] + Bb[c]);
    }
    *reinterpret_cast<uint4*>(&tb[t][u8]) = pk.v;
  }
  __syncthreads();
  const int j = t & 7;
#pragma unroll
  for (int rep = 0; rep < 8; ++rep) {
    const int p = rep * 32 + (t >> 3);
    const uint4 v = *reinterpret_cast<const uint4*>(&tb[p][j * 8]);
    *reinterpret_cast<uint4*>(fea + (size_t)(g0 + p) * 384 + c0 + j * 8) = v;
  }
}

// ---------------- K4: conv_w (OIHW f32) -> wb2 pre-staged order ----------------
// wb2 layout = [ct(2)][step(36)=cc*3+dy][slab(36)][lane(64)][8 bf16], matching
// k_conv's W staging exactly: slab row r = slab*16+(lane>>2) = tl*192+co_l,
// tap = dy*3+tl, ci = cc*32 + ((lane&3)^((co_l>>1)&3))*8 + u.
__global__ __launch_bounds__(256) void k_wcvt(const float* __restrict__ w,
                                              unsigned short* __restrict__ wb2) {
  const int g = blockIdx.x * 256 + threadIdx.x;  // 0..165887
  const int byte = g * 16;
  const int ct = byte / 1327104;
  const int r1 = byte - ct * 1327104;
  const int step = r1 / 36864;
  const int r2 = r1 - step * 36864;
  const int slab = r2 >> 10;
  const int lane = (r2 >> 4) & 63;
  const int cc = step / 3, dy = step - cc * 3;
  const int r = slab * 16 + (lane >> 2);         // 0..575
  const int tl = r / 192, co_l = r - tl * 192;
  const int co = ct * 192 + co_l;
  const int dd = (lane & 3) ^ ((co_l >> 1) & 3);
  const int tap = dy * 3 + tl;
  const int cib = cc * 32 + dd * 8;
  union { unsigned short us[8]; uint4 v4; } pk;
#pragma unroll
  for (int u = 0; u < 8; ++u)
    pk.us[u] = f2bf(w[(size_t)(co * 384 + cib + u) * 9 + tap]);
  *reinterpret_cast<uint4*>(wb2 + (size_t)g * 8) = pk.v4;
}

// ---------------- K5: implicit-GEMM conv + BN partial stats ----------------
// 512 thr = 8 waves = 2 co-groups x 4 pixel-quarters (2 waves/SIMD in ONE
// block -> intra-CU TLP). Block tile: 192co x 256pix (8 rows x 32 cols).
// Wave tile: 96co x 64pix = 6x4 frags 16x16x32 (acc 96 VGPR).
// K-step = (ci-chunk(32), dy): 12 x 3 = 36 steps, both operands DBUF'd:
//   [0,36864)        W buf 0: one (cc,dy) slice = 3 dx-taps x 192co x 32ci
//   [36864,73728)    W buf 1
//   [73728,99328)    IN buf 0: 20 data slabs (10 hrows x 32 col) + 5 ZERO slabs
//   [99328,124928)   IN buf 1 (same shape)
// Swizzle (R2-verified): 16B grp d of row r stored at d ^ ((r>>1)&3).
// Invalid-column B-reads land in the zero slabs (20480..25600 per buffer,
// covers +dy*2048). W staged linearly from the pre-arranged wb2 (1 ptr).
// Pipeline: stage(next) BEFORE compute(cur), one __syncthreads per step.
__global__ __launch_bounds__(512, 1) void k_conv(
    const unsigned short* __restrict__ fea, const unsigned short* __restrict__ wb2,
    const unsigned short* __restrict__ zpg, float* __restrict__ out,
    float* __restrict__ bn_sum, float* __restrict__ bn_sq) {
  __shared__ __align__(16) unsigned char lds[124928];
  const int tid = threadIdx.x;
  const int lane = tid & 63, wv = tid >> 6;      // wv 0..7
  const int wc = wv >> 2;                        // co group (0..1) -> 96 co
  const int wn = wv & 3;                         // pixel quarter (0..3)
  const int pt = blockIdx.x;                     // 0..127
  const int ct = blockIdx.y;                     // 0..1
  const int b = pt >> 2, h0 = (pt & 3) * 8;
  const int co0 = ct * 192;

  // ---- hoisted LDS read addresses ----
  const int l15 = lane & 15, d = lane >> 4;
  const int arow = wc * 96 + l15;
  const int aoff = arow * 64 + ((d ^ ((l15 >> 1) & 3)) << 4);
  int baddr[4][3];
#pragma unroll
  for (int n = 0; n < 4; ++n) {
    const int p_out = wn * 64 + n * 16 + l15;    // 0..255
    const int r_out = p_out >> 5, c_out = p_out & 31;
#pragma unroll
    for (int dx = 0; dx < 3; ++dx) {
      const int c = c_out + dx - 1;
      if ((unsigned)c < 32u) {
        const int row = r_out * 32 + c;
        baddr[n][dx] = row * 64 + ((d ^ ((row >> 1) & 3)) << 4);
      } else {
        baddr[n][dx] = 20480 + lane * 16;        // zero slabs (+dy*2048 safe)
      }
    }
  }

  // ---- W staging: single linear pointer into pre-arranged wb2 ----
  const unsigned short* wp =
      wb2 + (size_t)ct * 663552 + wv * 512 + lane * 8;   // elems
  // ---- IN staging pointers: role d stages slab d*8+wv of next chunk ----
  const unsigned short* ip[3];
  int istep[3];
#pragma unroll
  for (int dd2 = 0; dd2 < 3; ++dd2) {
    const int s = dd2 * 8 + wv;                  // 0..23, only <20 staged
    const int pix = s * 16 + (lane >> 2);
    const int prow = pix >> 5, pcol = pix & 31;
    const int h = h0 - 1 + prow;
    const int dg = (lane & 3) ^ ((pix >> 1) & 3);
    if (s < 20 && h >= 0 && h < 32) {
      ip[dd2] = fea + ((size_t)((b * 32 + h) * 32 + pcol) * 384 + dg * 8);
      istep[dd2] = 32;
    } else {
      ip[dd2] = zpg + lane * 8;                  // stage zeros
      istep[dd2] = 0;
    }
  }

  f32x4 acc[6][4] = {};

  // W slice stage into Wbuf at byte offset wo (slabs wv+8j, + slab 32+wv)
#define WSTAGE(wo)                                           \
  do {                                                       \
    gld16(wp,         lds + (wo) + wv * 1024);               \
    gld16(wp + 4096,  lds + (wo) + wv * 1024 + 8192);        \
    gld16(wp + 8192,  lds + (wo) + wv * 1024 + 16384);       \
    gld16(wp + 12288, lds + (wo) + wv * 1024 + 24576);       \
    if (wv < 4) gld16(wp + 16384, lds + (wo) + wv * 1024 + 32768); \
    wp += 18432;                                             \
  } while (0)

  // ---- prologue ----
  WSTAGE(0);                                     // step 0 -> Wbuf0
#pragma unroll
  for (int dd2 = 0; dd2 < 3; ++dd2) {            // IN chunk 0 -> IN0
    const int s = dd2 * 8 + wv;
    if (s < 20) { gld16(ip[dd2], lds + 73728 + s * 1024); ip[dd2] += istep[dd2]; }
  }
  if (wv < 5) {                                  // zero slabs, both buffers
    gld16(zpg + lane * 8, lds + 73728 + (20 + wv) * 1024);
    gld16(zpg + lane * 8, lds + 99328 + (20 + wv) * 1024);
  }
  __syncthreads();

  for (int cc = 0; cc < 12; ++cc) {
#pragma unroll
    for (int dy = 0; dy < 3; ++dy) {
      // stage W(next step) into the other W buffer
      if (!(cc == 11 && dy == 2)) WSTAGE(((cc + dy + 1) & 1) * 36864);
      // stage IN(chunk cc+1) slab dy*8+wv into the other IN buffer
      if (cc < 11) {
        const int s = dy * 8 + wv;
        if (s < 20) {
          gld16(ip[dy], lds + 73728 + ((cc + 1) & 1) * 25600 + s * 1024);
          ip[dy] += istep[dy];
        }
      }
      // compute 3 dx-taps of (cc, dy)
      const unsigned char* wbase = lds + ((cc + dy) & 1) * 36864;
      const unsigned char* ibase = lds + 73728 + (cc & 1) * 25600;
#pragma unroll
      for (int dx = 0; dx < 3; ++dx) {
        short8 af[6], bf[4];
#pragma unroll
        for (int m = 0; m < 6; ++m)
          af[m] = *reinterpret_cast<const short8*>(
              wbase + dx * 12288 + m * 1024 + aoff);
#pragma unroll
        for (int n = 0; n < 4; ++n)
          bf[n] = *reinterpret_cast<const short8*>(
              ibase + baddr[n][dx] + dy * 2048);
#pragma unroll
        for (int m = 0; m < 6; ++m)
#pragma unroll
          for (int n = 0; n < 4; ++n)
            acc[m][n] = __builtin_amdgcn_mfma_f32_16x16x32_bf16(
                af[m], bf[n], acc[m][n], 0, 0, 0);
      }
      __syncthreads();
    }
  }
#undef WSTAGE

  // ---- epilogue: store + BN partial stats (R5-verified) ----
  const size_t ob = (((size_t)b * 384 + co0) << 10) + h0 * 32;
#pragma unroll
  for (int m = 0; m < 6; ++m) {
#pragma unroll
    for (int r = 0; r < 4; ++r) {
      const int co = wc * 96 + m * 16 + d * 4 + r;   // within 192-co tile
      float s = 0.f, q = 0.f;
#pragma unroll
      for (int n = 0; n < 4; ++n) {
        const float v = acc[m][n][r];
        const int p = wn * 64 + n * 16 + l15;        // 0..255 in 8-row strip
        out[ob + ((size_t)co << 10) + p] = v;
        s += v; q += v * v;
      }
#pragma unroll
      for (int off = 1; off < 16; off <<= 1) {
        s += __shfl_xor(s, off, 64);
        q += __shfl_xor(q, off, 64);
      }
      if (l15 == 0) {
        atomicAdd(&bn_sum[co0 + co], s);
        atomicAdd(&bn_sq[co0 + co], q);
      }
    }
  }
}

// ---------------- K6: BN finalize in place ----------------
__global__ __launch_bounds__(256) void k_bnfin(float* __restrict__ y,
                                               const float* __restrict__ bn_sum,
                                               const float* __restrict__ bn_sq,
                                               const float* __restrict__ gamma,
                                               const float* __restrict__ beta) {
  const size_t N4 = (size_t)32 * 384 * 1024 / 4;
  const float inv = 1.0f / 32768.0f;
  for (size_t i = (size_t)blockIdx.x * 256 + threadIdx.x; i < N4;
       i += (size_t)gridDim.x * 256) {
    const size_t e = i * 4;
    const int c = (int)((e >> 10) % 384);
    const float mu = bn_sum[c] * inv;
    const float var = fmaxf(bn_sq[c] * inv - mu * mu, 0.0f);
    const float rs = rsqrtf(var + 1e-5f) * gamma[c];
    const float bt = beta[c];
    float4 v = *reinterpret_cast<float4*>(y + e);
    v.x = (v.x - mu) * rs + bt;
    v.y = (v.y - mu) * rs + bt;
    v.z = (v.z - mu) * rs + bt;
    v.w = (v.w - mu) * rs + bt;
    *reinterpret_cast<float4*>(y + e) = v;
  }
}

extern "C" void kernel_launch(void* const* d_in, const int* in_sizes, int n_in,
                              void* d_out, int out_size, void* d_ws, size_t ws_size,
                              hipStream_t stream) {
  const float* x     = (const float*)d_in[0];
  const float* pmp   = (const float*)d_in[1];
  const float* psp   = (const float*)d_in[2];
  const float* pmn   = (const float*)d_in[3];
  const float* psn   = (const float*)d_in[4];
  const float* cw    = (const float*)d_in[5];
  const float* convw = (const float*)d_in[6];
  const float* gamma = (const float*)d_in[7];
  const float* beta  = (const float*)d_in[8];
  const int*   label = (const int*)d_in[9];
  float* out = (float*)d_out;
  char* ws = (char*)d_ws;

  // ws layout (~28 MB total)
  unsigned short* fea = (unsigned short*)(ws);                 // 25165824 B
  unsigned short* wb2 = (unsigned short*)(ws + 25165824);      //  2654208 B
  float* sums  = (float*)(ws + 27820032);                      //    49152 B
  float* sumsq = (float*)(ws + 27869184);                      //    49152 B
  float* Ac    = (float*)(ws + 27918336);                      //    49152 B
  float* Bc    = (float*)(ws + 27967488);                      //    49152 B
  float* bn    = (float*)(ws + 28016640);                      //     3072 B
  float* zp    = (float*)(ws + 28019712);                      //     4096 B

  k_zero<<<dim3(1), dim3(256), 0, stream>>>(bn, zp);
  k_stats<<<dim3(12288), dim3(256), 0, stream>>>(x, sums, sumsq);
  k_coef<<<dim3(32), dim3(384), 0, stream>>>(pmp, psp, pmn, psn, cw, label,
                                             sums, sumsq, Ac, Bc);
  k_fea<<<dim3(128, 6), dim3(256), 0, stream>>>(x, Ac, Bc, fea);
  k_wcvt<<<dim3(648), dim3(256), 0, stream>>>(convw, wb2);
  k_conv<<<dim3(128, 2), dim3(512), 0, stream>>>(fea, wb2, (const unsigned short*)zp,
                                                 out, bn, bn + 384);
  k_bnfin<<<dim3(2048), dim3(256), 0, stream>>>(out, bn, bn + 384, gamma, beta);
}